// Round 1
// baseline (626.289 us; speedup 1.0000x reference)
//
#include <hip/hip_runtime.h>

// Problem constants (TargetModel_78786880077968: 2-layer GCN + mean pool)
#define NN 100000      // nodes
#define NE 1600000     // edges
#define NG 512         // graphs
#define FD 64          // feature dim (IN_DIM == HID == 64)
#define SCAN_CHUNK 1024
#define SCAN_BLOCKS 98  // ceil(NN / SCAN_CHUNK)

// ---------- CSR build ----------

__global__ void k_count(const int* __restrict__ dst, int* __restrict__ cnt, int e) {
    int i = blockIdx.x * 256 + threadIdx.x;
    if (i < e) atomicAdd(&cnt[dst[i]], 1);
}

// per-block exclusive scan of cnt (chunks of 1024), writes partial prefix + block sums
__global__ void k_scan1(const int* __restrict__ cnt, int* __restrict__ part,
                        int* __restrict__ blockSum, int n) {
    __shared__ int lds[256];
    int tid = threadIdx.x;
    int base = blockIdx.x * SCAN_CHUNK + tid * 4;
    int v0 = (base + 0 < n) ? cnt[base + 0] : 0;
    int v1 = (base + 1 < n) ? cnt[base + 1] : 0;
    int v2 = (base + 2 < n) ? cnt[base + 2] : 0;
    int v3 = (base + 3 < n) ? cnt[base + 3] : 0;
    int s = v0 + v1 + v2 + v3;
    lds[tid] = s;
    __syncthreads();
    for (int off = 1; off < 256; off <<= 1) {
        int t = (tid >= off) ? lds[tid - off] : 0;
        __syncthreads();
        lds[tid] += t;
        __syncthreads();
    }
    int run = lds[tid] - s;  // exclusive prefix of this thread within block
    if (base + 0 < n) part[base + 0] = run; run += v0;
    if (base + 1 < n) part[base + 1] = run; run += v1;
    if (base + 2 < n) part[base + 2] = run; run += v2;
    if (base + 3 < n) part[base + 3] = run;
    if (tid == 255) blockSum[blockIdx.x] = lds[255];
}

// single-block exclusive scan of block sums (nb <= 128)
__global__ void k_scan2(const int* __restrict__ bs, int* __restrict__ boff, int nb) {
    __shared__ int lds[128];
    int tid = threadIdx.x;
    int v = (tid < nb) ? bs[tid] : 0;
    lds[tid] = v;
    __syncthreads();
    for (int off = 1; off < 128; off <<= 1) {
        int t = (tid >= off) ? lds[tid - off] : 0;
        __syncthreads();
        lds[tid] += t;
        __syncthreads();
    }
    if (tid < nb) boff[tid] = lds[tid] - v;
}

// add block offsets -> rowptr; also init cursor = rowptr
__global__ void k_scan3(int* __restrict__ rowptr, const int* __restrict__ boff,
                        int* __restrict__ cursor, int n) {
    int i = blockIdx.x * 256 + threadIdx.x;
    if (i < n) {
        int r = rowptr[i] + boff[i >> 10];
        rowptr[i] = r;
        cursor[i] = r;
    }
}

__global__ void k_fill(const int* __restrict__ src, const int* __restrict__ dst,
                       int* __restrict__ cursor, int* __restrict__ colidx, int e) {
    int i = blockIdx.x * 256 + threadIdx.x;
    if (i < e) {
        int d = dst[i];
        int p = atomicAdd(&cursor[d], 1);
        colidx[p] = src[i];
    }
}

__global__ void k_dinv(const int* __restrict__ cnt, float* __restrict__ dinv, int n) {
    int i = blockIdx.x * 256 + threadIdx.x;
    if (i < n) {
        float deg = (float)(cnt[i] + 1);  // +1 self loop; always >= 1
        dinv[i] = 1.0f / sqrtf(deg);
    }
}

// ---------- dense: out[n][f] = dinv[n] * sum_k in[n][k] * W[k][f] ----------
// one wave per row; W staged in LDS (broadcast-read), x row staged in LDS.
__global__ void k_gemm_scale(const float* __restrict__ in, const float* __restrict__ W,
                             const float* __restrict__ dinv, float* __restrict__ out, int n) {
    __shared__ float w[FD * FD];
    __shared__ float xrow[4][FD];
    int tid = threadIdx.x;
    for (int i = tid; i < FD * FD; i += 256) w[i] = W[i];
    __syncthreads();
    int wave = tid >> 6, lane = tid & 63;
    int row = blockIdx.x * 4 + wave;
    if (row >= n) return;
    xrow[wave][lane] = in[row * FD + lane];
    float acc = 0.f;
#pragma unroll
    for (int k = 0; k < FD; ++k)
        acc = fmaf(xrow[wave][k], w[k * FD + lane], acc);
    out[row * FD + lane] = acc * dinv[row];
}

// ---------- aggregation: one wave per node, lane = feature ----------
// out[n][f] = relu( dinv[n] * (hs[n][f] + sum_{e: dst=n} hs[src_e][f]) + b[f] )
__global__ void k_agg_relu(const float* __restrict__ hs, const int* __restrict__ rowptr,
                           const int* __restrict__ cnt, const int* __restrict__ colidx,
                           const float* __restrict__ dinv, const float* __restrict__ b,
                           float* __restrict__ out, int n) {
    int tid = threadIdx.x;
    int wave = tid >> 6, lane = tid & 63;
    int node = blockIdx.x * 4 + wave;
    if (node >= n) return;
    float acc = hs[node * FD + lane];  // self loop
    int s = rowptr[node], e = s + cnt[node];
    int i = s;
    for (; i + 4 <= e; i += 4) {
        int s0 = colidx[i], s1 = colidx[i + 1], s2 = colidx[i + 2], s3 = colidx[i + 3];
        float a0 = hs[s0 * FD + lane];
        float a1 = hs[s1 * FD + lane];
        float a2 = hs[s2 * FD + lane];
        float a3 = hs[s3 * FD + lane];
        acc += (a0 + a1) + (a2 + a3);
    }
    for (; i < e; ++i) acc += hs[colidx[i] * FD + lane];
    float v = fmaxf(fmaf(acc, dinv[node], b[lane]), 0.0f);
    out[node * FD + lane] = v;
}

// same, but fuse global mean-pool accumulation (h2 never materialized)
__global__ void k_agg_pool(const float* __restrict__ hs, const int* __restrict__ rowptr,
                           const int* __restrict__ cnt, const int* __restrict__ colidx,
                           const float* __restrict__ dinv, const float* __restrict__ b,
                           const int* __restrict__ batch, float* __restrict__ pool, int n) {
    int tid = threadIdx.x;
    int wave = tid >> 6, lane = tid & 63;
    int node = blockIdx.x * 4 + wave;
    if (node >= n) return;
    float acc = hs[node * FD + lane];
    int s = rowptr[node], e = s + cnt[node];
    int i = s;
    for (; i + 4 <= e; i += 4) {
        int s0 = colidx[i], s1 = colidx[i + 1], s2 = colidx[i + 2], s3 = colidx[i + 3];
        float a0 = hs[s0 * FD + lane];
        float a1 = hs[s1 * FD + lane];
        float a2 = hs[s2 * FD + lane];
        float a3 = hs[s3 * FD + lane];
        acc += (a0 + a1) + (a2 + a3);
    }
    for (; i < e; ++i) acc += hs[colidx[i] * FD + lane];
    float v = fmaxf(fmaf(acc, dinv[node], b[lane]), 0.0f);
    atomicAdd(&pool[batch[node] * FD + lane], v);
}

__global__ void k_pcnt(const int* __restrict__ batch, int* __restrict__ pcnt, int n) {
    int i = blockIdx.x * 256 + threadIdx.x;
    if (i < n) atomicAdd(&pcnt[batch[i]], 1);
}

// out[g][o] = (sum_f pool[g][f]/cnt[g] * Wfc[f][o]) + bfc[o];  one wave per graph
__global__ void k_final(const float* __restrict__ pool, const int* __restrict__ pcnt,
                        const float* __restrict__ Wfc, const float* __restrict__ bfc,
                        float* __restrict__ out, int ng) {
    int tid = threadIdx.x;
    int wave = tid >> 6, lane = tid & 63;
    int g = blockIdx.x * 4 + wave;
    if (g >= ng) return;
    float inv = 1.0f / fmaxf((float)pcnt[g], 1.0f);
    float s = pool[g * FD + lane] * inv;
    float a0 = s * Wfc[lane * 2 + 0];
    float a1 = s * Wfc[lane * 2 + 1];
#pragma unroll
    for (int off = 32; off > 0; off >>= 1) {
        a0 += __shfl_down(a0, off, 64);
        a1 += __shfl_down(a1, off, 64);
    }
    if (lane == 0) {
        out[g * 2 + 0] = a0 + bfc[0];
        out[g * 2 + 1] = a1 + bfc[1];
    }
}

extern "C" void kernel_launch(void* const* d_in, const int* in_sizes, int n_in,
                              void* d_out, int out_size, void* d_ws, size_t ws_size,
                              hipStream_t stream) {
    const float* x    = (const float*)d_in[0];
    const int*   eidx = (const int*)d_in[1];   // [2][NE]: row0 = src, row1 = dst
    const int*   batch= (const int*)d_in[2];
    const float* W1   = (const float*)d_in[3];
    const float* b1   = (const float*)d_in[4];
    const float* W2   = (const float*)d_in[5];
    const float* b2   = (const float*)d_in[6];
    const float* Wfc  = (const float*)d_in[7];
    const float* bfc  = (const float*)d_in[8];
    float* out = (float*)d_out;

    const int* esrc = eidx;
    const int* edst = eidx + NE;

    // workspace carve-up (all offsets 256B-aligned)
    char* ws = (char*)d_ws;
    size_t off = 0;
    auto alloc = [&](size_t bytes) {
        char* p = ws + off;
        off += (bytes + 255) & ~(size_t)255;
        return p;
    };
    int*   cnt      = (int*)  alloc(NN * 4);
    int*   rowptr   = (int*)  alloc(NN * 4);
    int*   cursor   = (int*)  alloc(NN * 4);
    int*   blockSum = (int*)  alloc(128 * 4);
    int*   blockOff = (int*)  alloc(128 * 4);
    float* dinv     = (float*)alloc(NN * 4);
    int*   colidx   = (int*)  alloc((size_t)NE * 4);
    float* hs       = (float*)alloc((size_t)NN * FD * 4);
    float* h1       = (float*)alloc((size_t)NN * FD * 4);
    float* pool     = (float*)alloc((size_t)NG * FD * 4);
    int*   pcnt     = (int*)  alloc(NG * 4);
    (void)ws_size;

    hipMemsetAsync(cnt,  0, NN * 4, stream);
    hipMemsetAsync(pool, 0, (size_t)NG * FD * 4, stream);
    hipMemsetAsync(pcnt, 0, NG * 4, stream);

    const int GE = (NE + 255) / 256;   // 6250
    const int GN = (NN + 255) / 256;   // 391
    const int GW = (NN + 3) / 4;       // 25000 (wave-per-node/row kernels)

    k_count<<<GE, 256, 0, stream>>>(edst, cnt, NE);
    k_scan1<<<SCAN_BLOCKS, 256, 0, stream>>>(cnt, rowptr, blockSum, NN);
    k_scan2<<<1, 128, 0, stream>>>(blockSum, blockOff, SCAN_BLOCKS);
    k_scan3<<<GN, 256, 0, stream>>>(rowptr, blockOff, cursor, NN);
    k_fill<<<GE, 256, 0, stream>>>(esrc, edst, cursor, colidx, NE);
    k_dinv<<<GN, 256, 0, stream>>>(cnt, dinv, NN);

    // layer 1: hs = (x @ W1) * dinv ; h1 = relu(dinv * gather-sum(hs) + b1)
    k_gemm_scale<<<GW, 256, 0, stream>>>(x, W1, dinv, hs, NN);
    k_agg_relu<<<GW, 256, 0, stream>>>(hs, rowptr, cnt, colidx, dinv, b1, h1, NN);

    // layer 2: hs = (h1 @ W2) * dinv ; pool += relu(dinv * gather-sum(hs) + b2)
    k_gemm_scale<<<GW, 256, 0, stream>>>(h1, W2, dinv, hs, NN);
    k_pcnt<<<GN, 256, 0, stream>>>(batch, pcnt, NN);
    k_agg_pool<<<GW, 256, 0, stream>>>(hs, rowptr, cnt, colidx, dinv, b2, batch, pool, NN);

    // readout: out = (pool/cnt) @ Wfc + bfc
    k_final<<<(NG + 3) / 4, 256, 0, stream>>>(pool, pcnt, Wfc, bfc, out, NG);
}

// Round 2
// 564.993 us; speedup vs baseline: 1.1085x; 1.1085x over previous
//
#include <hip/hip_runtime.h>

// TargetModel_78786880077968: 2-layer GCN + mean pool
#define NN 100000      // nodes
#define NE 1600000     // edges
#define NG 512         // graphs
#define FD 64          // feature dim (IN_DIM == HID == 64)
#define SCAN_CHUNK 1024
#define SCAN_BLOCKS 98  // ceil(NN / SCAN_CHUNK)

// ---------- CSR build ----------

// count degree AND record each edge's rank within its dst bucket (coalesced write)
__global__ void k_count_rank(const int* __restrict__ dst, int* __restrict__ cnt,
                             int* __restrict__ rank, int e) {
    int i = blockIdx.x * 256 + threadIdx.x;
    if (i < e) rank[i] = atomicAdd(&cnt[dst[i]], 1);
}

// per-block exclusive scan of cnt (chunks of 1024), partial prefix + block sums
__global__ void k_scan1(const int* __restrict__ cnt, int* __restrict__ part,
                        int* __restrict__ blockSum, int n) {
    __shared__ int lds[256];
    int tid = threadIdx.x;
    int base = blockIdx.x * SCAN_CHUNK + tid * 4;
    int v0 = (base + 0 < n) ? cnt[base + 0] : 0;
    int v1 = (base + 1 < n) ? cnt[base + 1] : 0;
    int v2 = (base + 2 < n) ? cnt[base + 2] : 0;
    int v3 = (base + 3 < n) ? cnt[base + 3] : 0;
    int s = v0 + v1 + v2 + v3;
    lds[tid] = s;
    __syncthreads();
    for (int off = 1; off < 256; off <<= 1) {
        int t = (tid >= off) ? lds[tid - off] : 0;
        __syncthreads();
        lds[tid] += t;
        __syncthreads();
    }
    int run = lds[tid] - s;
    if (base + 0 < n) part[base + 0] = run; run += v0;
    if (base + 1 < n) part[base + 1] = run; run += v1;
    if (base + 2 < n) part[base + 2] = run; run += v2;
    if (base + 3 < n) part[base + 3] = run;
    if (tid == 255) blockSum[blockIdx.x] = lds[255];
}

__global__ void k_scan2(const int* __restrict__ bs, int* __restrict__ boff, int nb) {
    __shared__ int lds[128];
    int tid = threadIdx.x;
    int v = (tid < nb) ? bs[tid] : 0;
    lds[tid] = v;
    __syncthreads();
    for (int off = 1; off < 128; off <<= 1) {
        int t = (tid >= off) ? lds[tid - off] : 0;
        __syncthreads();
        lds[tid] += t;
        __syncthreads();
    }
    if (tid < nb) boff[tid] = lds[tid] - v;
}

// finalize rowptr; also dinv and per-graph node counts (folded launches)
__global__ void k_scan3(int* __restrict__ rowptr, const int* __restrict__ boff,
                        const int* __restrict__ cnt, float* __restrict__ dinv,
                        const int* __restrict__ batch, int* __restrict__ pcnt, int n) {
    int i = blockIdx.x * 256 + threadIdx.x;
    if (i < n) {
        rowptr[i] = rowptr[i] + boff[i >> 10];
        float deg = (float)(cnt[i] + 1);  // +1 self loop
        dinv[i] = 1.0f / sqrtf(deg);
        atomicAdd(&pcnt[batch[i]], 1);
    }
}

// atomic-free fill: position = rowptr[dst] + rank  (pure scatter write)
__global__ void k_fill(const int* __restrict__ src, const int* __restrict__ dst,
                       const int* __restrict__ rank, const int* __restrict__ rowptr,
                       int* __restrict__ colidx, int e) {
    int i = blockIdx.x * 256 + threadIdx.x;
    if (i < e) {
        int d = dst[i];
        colidx[rowptr[d] + rank[i]] = src[i];
    }
}

// ---------- dense: out[n][f] = dinv[n] * sum_k in[n][k] * W[k][f] ----------
// 4 waves/block, 4 rows/wave; lane = (row-in-wave, float4 chunk); W in LDS.
__global__ void k_gemm_scale(const float* __restrict__ in, const float* __restrict__ W,
                             const float* __restrict__ dinv, float* __restrict__ out, int n) {
    __shared__ float w[FD * FD];        // 16 KB
    __shared__ float xr[4][4][80];      // padded row staging (16B-aligned stride)
    int tid = threadIdx.x;
    // cooperative W load (float4)
    {
        const float4* W4 = (const float4*)W;
        float4* w4s = (float4*)w;
        for (int i = tid; i < FD * FD / 4; i += 256) w4s[i] = W4[i];
    }
    int wave = tid >> 6, lane = tid & 63;
    int r = lane >> 4;        // row within wave
    int c = lane & 15;        // float4 chunk
    int row = blockIdx.x * 16 + wave * 4 + r;
    bool valid = row < n;
    if (valid) {
        float4 xv = ((const float4*)in)[row * 16 + c];
        *((float4*)&xr[wave][r][c * 4]) = xv;
    }
    __syncthreads();
    if (!valid) return;
    const float4* w4 = (const float4*)w;   // w4[k*16 + c]
    float4 acc = {0.f, 0.f, 0.f, 0.f};
#pragma unroll
    for (int k = 0; k < FD; ++k) {
        float xv = xr[wave][r][k];
        float4 wv = w4[k * 16 + c];
        acc.x = fmaf(xv, wv.x, acc.x);
        acc.y = fmaf(xv, wv.y, acc.y);
        acc.z = fmaf(xv, wv.z, acc.z);
        acc.w = fmaf(xv, wv.w, acc.w);
    }
    float d = dinv[row];
    acc.x *= d; acc.y *= d; acc.z *= d; acc.w *= d;
    ((float4*)out)[row * 16 + c] = acc;
}

// ---------- aggregation: wave per node, float4 lanes, 4 rows/instruction ----------
// sum = hs[node] + sum_{e: dst=node} hs[src_e];  out = relu(dinv*sum + b)
template <int POOL>
__global__ void k_agg(const float* __restrict__ hs, const int* __restrict__ rowptr,
                      const int* __restrict__ cnt, const int* __restrict__ colidx,
                      const float* __restrict__ dinv, const float* __restrict__ b,
                      const int* __restrict__ batch, float* __restrict__ outp, int n) {
    int tid = threadIdx.x;
    int wave = tid >> 6, lane = tid & 63;
    int node = blockIdx.x * 4 + wave;
    if (node >= n) return;
    int g = lane >> 4;        // neighbor slot 0..3
    int c = lane & 15;        // float4 feature chunk
    const float4* hs4 = (const float4*)hs;
    float4 a0 = {0.f, 0.f, 0.f, 0.f};
    float4 a1 = {0.f, 0.f, 0.f, 0.f};
    int s = rowptr[node], e = s + cnt[node];
    int i = s;
    for (; i + 8 <= e; i += 8) {
        int n0 = colidx[i + g];
        int n1 = colidx[i + 4 + g];
        float4 v0 = hs4[n0 * 16 + c];
        float4 v1 = hs4[n1 * 16 + c];
        a0.x += v0.x; a0.y += v0.y; a0.z += v0.z; a0.w += v0.w;
        a1.x += v1.x; a1.y += v1.y; a1.z += v1.z; a1.w += v1.w;
    }
    for (; i < e; i += 4) {
        int j = i + g;
        if (j < e) {
            int nb = colidx[j];
            float4 v = hs4[nb * 16 + c];
            a0.x += v.x; a0.y += v.y; a0.z += v.z; a0.w += v.w;
        }
    }
    a0.x += a1.x; a0.y += a1.y; a0.z += a1.z; a0.w += a1.w;
#pragma unroll
    for (int off = 16; off <= 32; off <<= 1) {
        a0.x += __shfl_xor(a0.x, off, 64);
        a0.y += __shfl_xor(a0.y, off, 64);
        a0.z += __shfl_xor(a0.z, off, 64);
        a0.w += __shfl_xor(a0.w, off, 64);
    }
    // self loop + epilogue
    float4 self = hs4[node * 16 + c];
    a0.x += self.x; a0.y += self.y; a0.z += self.z; a0.w += self.w;
    float d = dinv[node];
    float4 bb = ((const float4*)b)[c];
    float4 res;
    res.x = fmaxf(fmaf(a0.x, d, bb.x), 0.f);
    res.y = fmaxf(fmaf(a0.y, d, bb.y), 0.f);
    res.z = fmaxf(fmaf(a0.z, d, bb.z), 0.f);
    res.w = fmaxf(fmaf(a0.w, d, bb.w), 0.f);
    if (g == 0) {
        if (POOL) {
            float* p = &outp[batch[node] * FD + c * 4];
            atomicAdd(p + 0, res.x);
            atomicAdd(p + 1, res.y);
            atomicAdd(p + 2, res.z);
            atomicAdd(p + 3, res.w);
        } else {
            ((float4*)outp)[node * 16 + c] = res;
        }
    }
}

// out[g][o] = (sum_f pool[g][f]/cnt[g] * Wfc[f][o]) + bfc[o];  wave per graph
__global__ void k_final(const float* __restrict__ pool, const int* __restrict__ pcnt,
                        const float* __restrict__ Wfc, const float* __restrict__ bfc,
                        float* __restrict__ out, int ng) {
    int tid = threadIdx.x;
    int wave = tid >> 6, lane = tid & 63;
    int g = blockIdx.x * 4 + wave;
    if (g >= ng) return;
    float inv = 1.0f / fmaxf((float)pcnt[g], 1.0f);
    float s = pool[g * FD + lane] * inv;
    float a0 = s * Wfc[lane * 2 + 0];
    float a1 = s * Wfc[lane * 2 + 1];
#pragma unroll
    for (int off = 32; off > 0; off >>= 1) {
        a0 += __shfl_down(a0, off, 64);
        a1 += __shfl_down(a1, off, 64);
    }
    if (lane == 0) {
        out[g * 2 + 0] = a0 + bfc[0];
        out[g * 2 + 1] = a1 + bfc[1];
    }
}

extern "C" void kernel_launch(void* const* d_in, const int* in_sizes, int n_in,
                              void* d_out, int out_size, void* d_ws, size_t ws_size,
                              hipStream_t stream) {
    const float* x    = (const float*)d_in[0];
    const int*   eidx = (const int*)d_in[1];   // [2][NE]: row0 = src, row1 = dst
    const int*   batch= (const int*)d_in[2];
    const float* W1   = (const float*)d_in[3];
    const float* b1   = (const float*)d_in[4];
    const float* W2   = (const float*)d_in[5];
    const float* b2   = (const float*)d_in[6];
    const float* Wfc  = (const float*)d_in[7];
    const float* bfc  = (const float*)d_in[8];
    float* out = (float*)d_out;

    const int* esrc = eidx;
    const int* edst = eidx + NE;

    char* ws = (char*)d_ws;
    size_t off = 0;
    auto alloc = [&](size_t bytes) {
        char* p = ws + off;
        off += (bytes + 255) & ~(size_t)255;
        return p;
    };
    int*   cnt      = (int*)  alloc(NN * 4);
    int*   rowptr   = (int*)  alloc(NN * 4);
    int*   blockSum = (int*)  alloc(128 * 4);
    int*   blockOff = (int*)  alloc(128 * 4);
    float* dinv     = (float*)alloc(NN * 4);
    int*   colidx   = (int*)  alloc((size_t)NE * 4);
    float* hs       = (float*)alloc((size_t)NN * FD * 4);
    float* h1       = (float*)alloc((size_t)NN * FD * 4);
    float* pool     = (float*)alloc((size_t)NG * FD * 4);
    int*   pcnt     = (int*)  alloc(NG * 4);
    // rank aliases h1: rank's last use (k_fill) precedes h1's first write (k_agg_relu)
    int*   rank     = (int*)h1;
    (void)ws_size;

    hipMemsetAsync(cnt,  0, NN * 4, stream);
    hipMemsetAsync(pool, 0, (size_t)NG * FD * 4, stream);
    hipMemsetAsync(pcnt, 0, NG * 4, stream);

    const int GE = (NE + 255) / 256;   // 6250
    const int GN = (NN + 255) / 256;   // 391
    const int GW = (NN + 3) / 4;       // wave-per-node kernels
    const int GR = (NN + 15) / 16;     // gemm: 16 rows/block

    k_count_rank<<<GE, 256, 0, stream>>>(edst, cnt, rank, NE);
    k_scan1<<<SCAN_BLOCKS, 256, 0, stream>>>(cnt, rowptr, blockSum, NN);
    k_scan2<<<1, 128, 0, stream>>>(blockSum, blockOff, SCAN_BLOCKS);
    k_scan3<<<GN, 256, 0, stream>>>(rowptr, blockOff, cnt, dinv, batch, pcnt, NN);
    k_fill<<<GE, 256, 0, stream>>>(esrc, edst, rank, rowptr, colidx, NE);

    // layer 1
    k_gemm_scale<<<GR, 256, 0, stream>>>(x, W1, dinv, hs, NN);
    k_agg<0><<<GW, 256, 0, stream>>>(hs, rowptr, cnt, colidx, dinv, b1, batch, h1, NN);

    // layer 2 (pool fused into aggregation epilogue)
    k_gemm_scale<<<GR, 256, 0, stream>>>(h1, W2, dinv, hs, NN);
    k_agg<1><<<GW, 256, 0, stream>>>(hs, rowptr, cnt, colidx, dinv, b2, batch, pool, NN);

    // readout
    k_final<<<(NG + 3) / 4, 256, 0, stream>>>(pool, pcnt, Wfc, bfc, out, NG);
}